// Round 1
// baseline (193.241 us; speedup 1.0000x reference)
//
#include <hip/hip_runtime.h>

#define BB 8
#define SS 4096
#define DD 256
#define NEGV -1000000000.0f

typedef float f32x4 __attribute__((ext_vector_type(4)));
typedef short s16x8 __attribute__((ext_vector_type(8)));

// float -> bf16 round-to-nearest-even (inputs are finite; no NaN handling needed)
static __device__ __forceinline__ unsigned short f2bf(float x) {
  unsigned int u = __builtin_bit_cast(unsigned int, x);
  u += 0x7fffu + ((u >> 16) & 1u);
  return (unsigned short)(u >> 16);
}

// ---------------------------------------------------------------------------
// Kernel 1 (prep): per-row norms + mask folding.
//   QS[b][s][d]  = bf16( mask ? NEG : q/sum(q^2) )      (natural [s][d])
//   KT[b][d][s]  = bf16( k / sum(k^2) )                 (transposed)
//   VT[b][e][s]  = bf16( v )                            (transposed)
// One wave per row (64 lanes x float4 = 256 elems). Transpose via LDS.
// ---------------------------------------------------------------------------
__global__ __launch_bounds__(256) void prep_kernel(
    const float* __restrict__ Q, const float* __restrict__ K,
    const float* __restrict__ V, const int* __restrict__ mask,
    unsigned short* __restrict__ QS, unsigned short* __restrict__ KT,
    unsigned short* __restrict__ VT) {
  __shared__ unsigned short tile[DD * 68];  // [d][s_local], stride 68 (64 + pad)
  const int b = blockIdx.y;
  const int s_base = blockIdx.x * 64;
  const int tid = threadIdx.x;
  const int w = tid >> 6;
  const int l = tid & 63;

  // ---- Q phase: score rows (no transpose needed)
  for (int it = 0; it < 16; ++it) {
    const int s = s_base + w * 16 + it;
    const size_t rowo = ((size_t)b * SS + s) * DD;
    const float4 q = *(const float4*)(Q + rowo + l * 4);
    float ss = q.x * q.x + q.y * q.y + q.z * q.z + q.w * q.w;
#pragma unroll
    for (int off = 32; off; off >>= 1) ss += __shfl_xor(ss, off);
    const int m = mask[b * SS + s];
    const float ca = m ? 0.0f : (1.0f / ss);
    const float aa = m ? NEGV : 0.0f;
    ushort4 o;
    o.x = f2bf(q.x * ca + aa);
    o.y = f2bf(q.y * ca + aa);
    o.z = f2bf(q.z * ca + aa);
    o.w = f2bf(q.w * ca + aa);
    *(ushort4*)(QS + rowo + l * 4) = o;
  }

  // ---- K phase: scale by 1/sum(k^2), stage transposed in LDS
  for (int it = 0; it < 16; ++it) {
    const int sl = w * 16 + it;
    const int s = s_base + sl;
    const float4 k = *(const float4*)(K + ((size_t)b * SS + s) * DD + l * 4);
    float ss = k.x * k.x + k.y * k.y + k.z * k.z + k.w * k.w;
#pragma unroll
    for (int off = 32; off; off >>= 1) ss += __shfl_xor(ss, off);
    const float binv = 1.0f / ss;
    tile[(l * 4 + 0) * 68 + sl] = f2bf(k.x * binv);
    tile[(l * 4 + 1) * 68 + sl] = f2bf(k.y * binv);
    tile[(l * 4 + 2) * 68 + sl] = f2bf(k.z * binv);
    tile[(l * 4 + 3) * 68 + sl] = f2bf(k.w * binv);
  }
  __syncthreads();
  {  // flush K~T: thread tid owns d-row tid, 64 bf16 = 128B contiguous
    const size_t base = ((size_t)b * DD + tid) * SS + s_base;
#pragma unroll
    for (int c = 0; c < 8; ++c) {
      const uint2 a = *(const uint2*)(tile + tid * 68 + c * 8);
      const uint2 b2 = *(const uint2*)(tile + tid * 68 + c * 8 + 4);
      uint4 vv;
      vv.x = a.x; vv.y = a.y; vv.z = b2.x; vv.w = b2.y;
      *(uint4*)(KT + base + c * 8) = vv;
    }
  }
  __syncthreads();

  // ---- V phase: plain convert, transposed
  for (int it = 0; it < 16; ++it) {
    const int sl = w * 16 + it;
    const int s = s_base + sl;
    const float4 v = *(const float4*)(V + ((size_t)b * SS + s) * DD + l * 4);
    tile[(l * 4 + 0) * 68 + sl] = f2bf(v.x);
    tile[(l * 4 + 1) * 68 + sl] = f2bf(v.y);
    tile[(l * 4 + 2) * 68 + sl] = f2bf(v.z);
    tile[(l * 4 + 3) * 68 + sl] = f2bf(v.w);
  }
  __syncthreads();
  {
    const size_t base = ((size_t)b * DD + tid) * SS + s_base;
#pragma unroll
    for (int c = 0; c < 8; ++c) {
      const uint2 a = *(const uint2*)(tile + tid * 68 + c * 8);
      const uint2 b2 = *(const uint2*)(tile + tid * 68 + c * 8 + 4);
      uint4 vv;
      vv.x = a.x; vv.y = a.y; vv.z = b2.x; vv.w = b2.y;
      *(uint4*)(VT + base + c * 8) = vv;
    }
  }
}

// ---------------------------------------------------------------------------
// Kernel 2: s1T[b][e][d] = sum_s VT[e][s] * KT[d][s]   (MFMA, split-K over s)
// A-operand = VT (m = e), B-operand = KT (n = d) -> D[e][d] = s1 TRANSPOSED,
// which is exactly the layout kernel 3's B-operand wants.
// ---------------------------------------------------------------------------
__global__ __launch_bounds__(256) void p2_kernel(
    const unsigned short* __restrict__ KT, const unsigned short* __restrict__ VT,
    float* __restrict__ s1T) {
  __shared__ unsigned short vt_l[128 * 40];  // [e_local][s_local 32 + pad 8]
  __shared__ unsigned short kt_l[128 * 40];  // [d_local][s_local]
  const int b = blockIdx.z;
  const int d0 = (blockIdx.x & 1) * 128;
  const int e0 = (blockIdx.x >> 1) * 128;
  const int sbeg = blockIdx.y * 512;
  const int tid = threadIdx.x;
  const int w = tid >> 6, l = tid & 63;
  const int wr = w & 1, wc = w >> 1;  // wave sub-tile: e += wr*64, d += wc*64
  const int quad = l >> 4, mr = l & 15;

  f32x4 acc[4][4];
#pragma unroll
  for (int i = 0; i < 4; ++i)
#pragma unroll
    for (int j = 0; j < 4; ++j) acc[i][j] = (f32x4){0.f, 0.f, 0.f, 0.f};

  const size_t vbase = ((size_t)b * DD + e0) * SS;
  const size_t kbase = ((size_t)b * DD + d0) * SS;

  for (int ks = 0; ks < 16; ++ks) {
    const int sc = sbeg + ks * 32;
#pragma unroll
    for (int it = 0; it < 2; ++it) {
      const int flat = it * 256 + tid;
      const int row = flat >> 2;
      const int c8 = (flat & 3) * 8;
      *(uint4*)(vt_l + row * 40 + c8) =
          *(const uint4*)(VT + vbase + (size_t)row * SS + sc + c8);
      *(uint4*)(kt_l + row * 40 + c8) =
          *(const uint4*)(KT + kbase + (size_t)row * SS + sc + c8);
    }
    __syncthreads();
    s16x8 af[4], bfr[4];
#pragma unroll
    for (int i = 0; i < 4; ++i)
      af[i] = *(const s16x8*)(vt_l + (wr * 64 + i * 16 + mr) * 40 + quad * 8);
#pragma unroll
    for (int j = 0; j < 4; ++j)
      bfr[j] = *(const s16x8*)(kt_l + (wc * 64 + j * 16 + mr) * 40 + quad * 8);
#pragma unroll
    for (int i = 0; i < 4; ++i)
#pragma unroll
      for (int j = 0; j < 4; ++j)
        acc[i][j] = __builtin_amdgcn_mfma_f32_16x16x32_bf16(af[i], bfr[j],
                                                            acc[i][j], 0, 0, 0);
    __syncthreads();
  }

  // epilogue: D row = e (quad*4 + r), col = d (mr); atomic split-K reduce
#pragma unroll
  for (int i = 0; i < 4; ++i) {
    const int e = e0 + wr * 64 + i * 16 + quad * 4;
#pragma unroll
    for (int j = 0; j < 4; ++j) {
      const int d = d0 + wc * 64 + j * 16 + mr;
      float* p = s1T + ((size_t)b * DD + e) * DD + d;
#pragma unroll
      for (int r = 0; r < 4; ++r) atomicAdd(p + (size_t)r * DD, acc[i][j][r]);
    }
  }
}

// ---------------------------------------------------------------------------
// Kernel 3: out[b][s][e] = (1/D) * sum_d QS[s][d] * s1T[e][d]
// A-operand = QS (m = s, k = d contiguous), B-operand = s1T rows (n = e,
// k = d contiguous). s1T fp32 -> bf16 conversion fused into LDS staging.
// ---------------------------------------------------------------------------
__global__ __launch_bounds__(256) void p3_kernel(
    const unsigned short* __restrict__ QS, const float* __restrict__ s1T,
    float* __restrict__ out) {
  __shared__ unsigned short qs_l[128 * 40];  // [s_local][d_local 32 + pad]
  __shared__ unsigned short s1_l[128 * 40];  // [e_local][d_local]
  const int b = blockIdx.z;
  const int e0 = blockIdx.x * 128;
  const int s0 = blockIdx.y * 128;
  const int tid = threadIdx.x;
  const int w = tid >> 6, l = tid & 63;
  const int wr = w & 1, wc = w >> 1;  // wave sub-tile: s += wr*64, e += wc*64
  const int quad = l >> 4, mr = l & 15;

  f32x4 acc[4][4];
#pragma unroll
  for (int i = 0; i < 4; ++i)
#pragma unroll
    for (int j = 0; j < 4; ++j) acc[i][j] = (f32x4){0.f, 0.f, 0.f, 0.f};

  for (int ks = 0; ks < 8; ++ks) {
    const int dc = ks * 32;
#pragma unroll
    for (int it = 0; it < 2; ++it) {
      const int flat = it * 256 + tid;
      const int row = flat >> 2;
      const int c8 = (flat & 3) * 8;
      *(uint4*)(qs_l + row * 40 + c8) =
          *(const uint4*)(QS + ((size_t)b * SS + s0 + row) * DD + dc + c8);
    }
#pragma unroll
    for (int it = 0; it < 4; ++it) {
      const int flat = it * 256 + tid;
      const int row = flat >> 3;
      const int c4 = (flat & 7) * 4;
      const float4 sv =
          *(const float4*)(s1T + ((size_t)b * DD + e0 + row) * DD + dc + c4);
      ushort4 o;
      o.x = f2bf(sv.x); o.y = f2bf(sv.y); o.z = f2bf(sv.z); o.w = f2bf(sv.w);
      *(ushort4*)(s1_l + row * 40 + c4) = o;
    }
    __syncthreads();
    s16x8 af[4], bfr[4];
#pragma unroll
    for (int i = 0; i < 4; ++i)
      af[i] = *(const s16x8*)(qs_l + (wr * 64 + i * 16 + mr) * 40 + quad * 8);
#pragma unroll
    for (int j = 0; j < 4; ++j)
      bfr[j] = *(const s16x8*)(s1_l + (wc * 64 + j * 16 + mr) * 40 + quad * 8);
#pragma unroll
    for (int i = 0; i < 4; ++i)
#pragma unroll
      for (int j = 0; j < 4; ++j)
        acc[i][j] = __builtin_amdgcn_mfma_f32_16x16x32_bf16(af[i], bfr[j],
                                                            acc[i][j], 0, 0, 0);
    __syncthreads();
  }

  // epilogue: D row = s (quad*4 + r), col = e (mr)
#pragma unroll
  for (int i = 0; i < 4; ++i) {
    const int s = s0 + wr * 64 + i * 16 + quad * 4;
#pragma unroll
    for (int j = 0; j < 4; ++j) {
      const int e = e0 + wc * 64 + j * 16 + mr;
      float* p = out + ((size_t)b * SS + s) * DD + e;
#pragma unroll
      for (int r = 0; r < 4; ++r) p[(size_t)r * DD] = acc[i][j][r] * (1.0f / DD);
    }
  }
}

extern "C" void kernel_launch(void* const* d_in, const int* in_sizes, int n_in,
                              void* d_out, int out_size, void* d_ws,
                              size_t ws_size, hipStream_t stream) {
  const float* Q = (const float*)d_in[0];
  const float* K = (const float*)d_in[1];
  const float* V = (const float*)d_in[2];
  const int* mask = (const int*)d_in[3];
  float* out = (float*)d_out;

  char* ws = (char*)d_ws;
  const size_t MB16 = (size_t)16 * 1024 * 1024;
  unsigned short* QS = (unsigned short*)(ws);             // bf16 [B][S][D] 16MB
  unsigned short* KT = (unsigned short*)(ws + MB16);      // bf16 [B][D][S] 16MB
  unsigned short* VT = (unsigned short*)(ws + 2 * MB16);  // bf16 [B][D][S] 16MB
  float* s1T = (float*)(ws + 3 * MB16);                   // f32  [B][D][D]  2MB

  hipMemsetAsync(s1T, 0, (size_t)BB * DD * DD * sizeof(float), stream);
  prep_kernel<<<dim3(SS / 64, BB), 256, 0, stream>>>(Q, K, V, mask, QS, KT, VT);
  p2_kernel<<<dim3(4, 8, BB), 256, 0, stream>>>(KT, VT, s1T);
  p3_kernel<<<dim3(2, SS / 128, BB), 256, 0, stream>>>(QS, s1T, out);
}

// Round 2
// 185.296 us; speedup vs baseline: 1.0429x; 1.0429x over previous
//
#include <hip/hip_runtime.h>

#define BB 8
#define SS 4096
#define DD 256
#define NEGV -1000000000.0f

typedef float f32x4 __attribute__((ext_vector_type(4)));
typedef short s16x8 __attribute__((ext_vector_type(8)));

// float -> bf16 round-to-nearest-even (inputs finite)
static __device__ __forceinline__ unsigned short f2bf(float x) {
  unsigned int u = __builtin_bit_cast(unsigned int, x);
  u += 0x7fffu + ((u >> 16) & 1u);
  return (unsigned short)(u >> 16);
}

// ---------------------------------------------------------------------------
// prep: grid (S/32, B, 3). z=0: QS natural (no LDS). z=1: KT, z=2: VT
// (transposed via LDS, conflict-free: lane l owns d = l + 64c, row stride
// 34 halfwords -> bank = 17*l mod 32, full spread).
// ---------------------------------------------------------------------------
__global__ __launch_bounds__(256) void prep_kernel(
    const float* __restrict__ Q, const float* __restrict__ K,
    const float* __restrict__ V, const int* __restrict__ mask,
    unsigned short* __restrict__ QS, unsigned short* __restrict__ KT,
    unsigned short* __restrict__ VT) {
  __shared__ unsigned short tile[DD * 34];
  const int b = blockIdx.y;
  const int s0 = blockIdx.x * 32;
  const int tid = threadIdx.x;
  const int w = tid >> 6, l = tid & 63;

  if (blockIdx.z == 0) {  // ---- Q path: pure streaming
#pragma unroll
    for (int it = 0; it < 8; ++it) {
      const int s = s0 + w * 8 + it;
      const size_t rowo = ((size_t)b * SS + s) * DD;
      const float4 q = *(const float4*)(Q + rowo + l * 4);
      float ss = q.x * q.x + q.y * q.y + q.z * q.z + q.w * q.w;
#pragma unroll
      for (int off = 32; off; off >>= 1) ss += __shfl_xor(ss, off);
      const int m = mask[b * SS + s];
      const float ca = m ? 0.0f : (1.0f / ss);
      const float aa = m ? NEGV : 0.0f;
      ushort4 o;
      o.x = f2bf(q.x * ca + aa);
      o.y = f2bf(q.y * ca + aa);
      o.z = f2bf(q.z * ca + aa);
      o.w = f2bf(q.w * ca + aa);
      *(ushort4*)(QS + rowo + l * 4) = o;
    }
    return;
  }

  const int isK = (blockIdx.z == 1);
  const float* __restrict__ src = isK ? K : V;
  unsigned short* __restrict__ dst = isK ? KT : VT;

#pragma unroll
  for (int it = 0; it < 8; ++it) {
    const int sl = w * 8 + it;
    const size_t rowo = ((size_t)b * SS + s0 + sl) * DD;
    const float v0 = src[rowo + l];
    const float v1 = src[rowo + l + 64];
    const float v2 = src[rowo + l + 128];
    const float v3 = src[rowo + l + 192];
    float ss = v0 * v0 + v1 * v1 + v2 * v2 + v3 * v3;
#pragma unroll
    for (int off = 32; off; off >>= 1) ss += __shfl_xor(ss, off);
    const float sc = isK ? (1.0f / ss) : 1.0f;
    tile[(l) * 34 + sl] = f2bf(v0 * sc);
    tile[(l + 64) * 34 + sl] = f2bf(v1 * sc);
    tile[(l + 128) * 34 + sl] = f2bf(v2 * sc);
    tile[(l + 192) * 34 + sl] = f2bf(v3 * sc);
  }
  __syncthreads();
  // flush: thread tid owns d-row tid -> 32 halfwords = 64B contiguous
  const size_t base = ((size_t)b * DD + tid) * SS + s0;
#pragma unroll
  for (int c = 0; c < 4; ++c) {
    uint4 vv;
    vv.x = *(const unsigned int*)(tile + tid * 34 + c * 8 + 0);
    vv.y = *(const unsigned int*)(tile + tid * 34 + c * 8 + 2);
    vv.z = *(const unsigned int*)(tile + tid * 34 + c * 8 + 4);
    vv.w = *(const unsigned int*)(tile + tid * 34 + c * 8 + 6);
    *(uint4*)(dst + base + c * 8) = vv;
  }
}

// ---------------------------------------------------------------------------
// p2: part[y][b][e][d] = sum_{s in chunk y} VT[e][s]*KT[d][s]. Plain stores.
// ---------------------------------------------------------------------------
__global__ __launch_bounds__(256) void p2_kernel(
    const unsigned short* __restrict__ KT, const unsigned short* __restrict__ VT,
    float* __restrict__ part, int nks) {
  __shared__ unsigned short vt_l[128 * 40];
  __shared__ unsigned short kt_l[128 * 40];
  const int b = blockIdx.z;
  const int d0 = (blockIdx.x & 1) * 128;
  const int e0 = (blockIdx.x >> 1) * 128;
  const int sbeg = blockIdx.y * nks * 32;
  const int tid = threadIdx.x;
  const int w = tid >> 6, l = tid & 63;
  const int wr = w & 1, wc = w >> 1;
  const int quad = l >> 4, mr = l & 15;

  f32x4 acc[4][4];
#pragma unroll
  for (int i = 0; i < 4; ++i)
#pragma unroll
    for (int j = 0; j < 4; ++j) acc[i][j] = (f32x4){0.f, 0.f, 0.f, 0.f};

  const size_t vbase = ((size_t)b * DD + e0) * SS;
  const size_t kbase = ((size_t)b * DD + d0) * SS;

  for (int ks = 0; ks < nks; ++ks) {
    const int sc = sbeg + ks * 32;
#pragma unroll
    for (int it = 0; it < 2; ++it) {
      const int flat = it * 256 + tid;
      const int row = flat >> 2;
      const int c8 = (flat & 3) * 8;
      *(uint4*)(vt_l + row * 40 + c8) =
          *(const uint4*)(VT + vbase + (size_t)row * SS + sc + c8);
      *(uint4*)(kt_l + row * 40 + c8) =
          *(const uint4*)(KT + kbase + (size_t)row * SS + sc + c8);
    }
    __syncthreads();
    s16x8 af[4], bfr[4];
#pragma unroll
    for (int i = 0; i < 4; ++i)
      af[i] = *(const s16x8*)(vt_l + (wr * 64 + i * 16 + mr) * 40 + quad * 8);
#pragma unroll
    for (int j = 0; j < 4; ++j)
      bfr[j] = *(const s16x8*)(kt_l + (wc * 64 + j * 16 + mr) * 40 + quad * 8);
#pragma unroll
    for (int i = 0; i < 4; ++i)
#pragma unroll
      for (int j = 0; j < 4; ++j)
        acc[i][j] = __builtin_amdgcn_mfma_f32_16x16x32_bf16(af[i], bfr[j],
                                                            acc[i][j], 0, 0, 0);
    __syncthreads();
  }

  float* pb = part + (((size_t)blockIdx.y * BB + b) * DD) * DD;
#pragma unroll
  for (int i = 0; i < 4; ++i) {
    const int e = e0 + wr * 64 + i * 16 + quad * 4;
#pragma unroll
    for (int j = 0; j < 4; ++j) {
      const int d = d0 + wc * 64 + j * 16 + mr;
      float* p = pb + (size_t)e * DD + d;
#pragma unroll
      for (int r = 0; r < 4; ++r) p[(size_t)r * DD] = acc[i][j][r];
    }
  }
}

// ---------------------------------------------------------------------------
// reduce: s1b[b][e][d] (bf16) = sum_p part[p][b][e][d]. L2-resident.
// ---------------------------------------------------------------------------
__global__ __launch_bounds__(256) void reduce_kernel(
    const float* __restrict__ part, unsigned short* __restrict__ s1b,
    int split) {
  const size_t i4 = ((size_t)blockIdx.x * 256 + threadIdx.x) * 4;
  float ax = 0.f, ay = 0.f, az = 0.f, aw = 0.f;
  for (int p = 0; p < split; ++p) {
    const float4 v = *(const float4*)(part + (size_t)p * (BB * DD * DD) + i4);
    ax += v.x; ay += v.y; az += v.z; aw += v.w;
  }
  ushort4 o;
  o.x = f2bf(ax); o.y = f2bf(ay); o.z = f2bf(az); o.w = f2bf(aw);
  *(ushort4*)(s1b + i4) = o;
}

// ---------------------------------------------------------------------------
// p3: out[b][s][e] = (1/D) * sum_d QS[s][d] * s1b[e][d]
// ---------------------------------------------------------------------------
__global__ __launch_bounds__(256) void p3_kernel(
    const unsigned short* __restrict__ QS, const unsigned short* __restrict__ s1b,
    float* __restrict__ out) {
  __shared__ unsigned short qs_l[128 * 40];
  __shared__ unsigned short s1_l[128 * 40];
  const int b = blockIdx.z;
  const int e0 = blockIdx.x * 128;
  const int s0 = blockIdx.y * 128;
  const int tid = threadIdx.x;
  const int w = tid >> 6, l = tid & 63;
  const int wr = w & 1, wc = w >> 1;
  const int quad = l >> 4, mr = l & 15;

  f32x4 acc[4][4];
#pragma unroll
  for (int i = 0; i < 4; ++i)
#pragma unroll
    for (int j = 0; j < 4; ++j) acc[i][j] = (f32x4){0.f, 0.f, 0.f, 0.f};

  for (int ks = 0; ks < 8; ++ks) {
    const int dc = ks * 32;
#pragma unroll
    for (int it = 0; it < 2; ++it) {
      const int flat = it * 256 + tid;
      const int row = flat >> 2;
      const int c8 = (flat & 3) * 8;
      *(uint4*)(qs_l + row * 40 + c8) =
          *(const uint4*)(QS + ((size_t)b * SS + s0 + row) * DD + dc + c8);
      *(uint4*)(s1_l + row * 40 + c8) =
          *(const uint4*)(s1b + ((size_t)b * DD + e0 + row) * DD + dc + c8);
    }
    __syncthreads();
    s16x8 af[4], bfr[4];
#pragma unroll
    for (int i = 0; i < 4; ++i)
      af[i] = *(const s16x8*)(qs_l + (wr * 64 + i * 16 + mr) * 40 + quad * 8);
#pragma unroll
    for (int j = 0; j < 4; ++j)
      bfr[j] = *(const s16x8*)(s1_l + (wc * 64 + j * 16 + mr) * 40 + quad * 8);
#pragma unroll
    for (int i = 0; i < 4; ++i)
#pragma unroll
      for (int j = 0; j < 4; ++j)
        acc[i][j] = __builtin_amdgcn_mfma_f32_16x16x32_bf16(af[i], bfr[j],
                                                            acc[i][j], 0, 0, 0);
    __syncthreads();
  }

#pragma unroll
  for (int i = 0; i < 4; ++i) {
    const int s = s0 + wr * 64 + i * 16 + quad * 4;
#pragma unroll
    for (int j = 0; j < 4; ++j) {
      const int e = e0 + wc * 64 + j * 16 + mr;
      float* p = out + ((size_t)b * SS + s) * DD + e;
#pragma unroll
      for (int r = 0; r < 4; ++r) p[(size_t)r * DD] = acc[i][j][r] * (1.0f / DD);
    }
  }
}

extern "C" void kernel_launch(void* const* d_in, const int* in_sizes, int n_in,
                              void* d_out, int out_size, void* d_ws,
                              size_t ws_size, hipStream_t stream) {
  const float* Q = (const float*)d_in[0];
  const float* K = (const float*)d_in[1];
  const float* V = (const float*)d_in[2];
  const int* mask = (const int*)d_in[3];
  float* out = (float*)d_out;

  char* ws = (char*)d_ws;
  const size_t MB = (size_t)1024 * 1024;
  unsigned short* QS = (unsigned short*)(ws);            // bf16 [B][S][D] 16MB
  unsigned short* KT = (unsigned short*)(ws + 16 * MB);  // bf16 [B][D][S] 16MB
  unsigned short* VT = (unsigned short*)(ws + 32 * MB);  // bf16 [B][D][S] 16MB
  float* part = (float*)(ws + 48 * MB);                  // f32 [split][B][D][D]

  // split-K factor sized to available workspace (partials = 2MB each)
  const int split = (ws_size >= (size_t)84 * MB) ? 16 : 8;
  const int nks = SS / (32 * split);
  unsigned short* s1b =
      (unsigned short*)(ws + 48 * MB + (size_t)split * 2 * MB);  // bf16 1MB

  prep_kernel<<<dim3(SS / 32, BB, 3), 256, 0, stream>>>(Q, K, V, mask, QS, KT,
                                                        VT);
  p2_kernel<<<dim3(4, split, BB), 256, 0, stream>>>(KT, VT, part, nks);
  reduce_kernel<<<dim3(512), 256, 0, stream>>>(part, s1b, split);
  p3_kernel<<<dim3(2, SS / 128, BB), 256, 0, stream>>>(QS, s1b, out);
}

// Round 3
// 180.074 us; speedup vs baseline: 1.0731x; 1.0290x over previous
//
#include <hip/hip_runtime.h>

#define BB 8
#define SS 4096
#define DD 256
#define NEGV -1000000000.0f

typedef float f32x4 __attribute__((ext_vector_type(4)));
typedef short s16x8 __attribute__((ext_vector_type(8)));

// float -> bf16 round-to-nearest-even (inputs finite)
static __device__ __forceinline__ unsigned short f2bf(float x) {
  unsigned int u = __builtin_bit_cast(unsigned int, x);
  u += 0x7fffu + ((u >> 16) & 1u);
  return (unsigned short)(u >> 16);
}

// async global->LDS, 16B per lane; LDS dest = wave-uniform base + lane*16
static __device__ __forceinline__ void gload_lds16(
    const unsigned short* __restrict__ g, unsigned short* l) {
  __builtin_amdgcn_global_load_lds(
      (const __attribute__((address_space(1))) void*)g,
      (__attribute__((address_space(3))) void*)l, 16, 0, 0);
}

// ---------------------------------------------------------------------------
// prep: grid (S/64, B, 3).
//  z=0: QS[b][s][d] = bf16(mask ? NEG : q/|q|^2)   (natural, no LDS)
//  z=1: KT[b][d][s] = bf16(k/|k|^2)                (LDS transpose)
//  z=2: VT[b][e][s] = bf16(v)                      (LDS transpose)
// 16 float4 loads/thread in flight; norms via 16 ILP'd shuffle trees;
// LDS tile [64 s][260 hw]: b64 writes 2-way (free), transposed u16 reads
// conflict-free (dword = s*130 + t/2 covers all 32 banks).
// ---------------------------------------------------------------------------
__global__ __launch_bounds__(256) void prep_kernel(
    const float* __restrict__ Q, const float* __restrict__ K,
    const float* __restrict__ V, const int* __restrict__ mask,
    unsigned short* __restrict__ QS, unsigned short* __restrict__ KT,
    unsigned short* __restrict__ VT) {
  __shared__ unsigned short tile[64 * 260];
  const int b = blockIdx.y;
  const int s0 = blockIdx.x * 64;
  const int tid = threadIdx.x;
  const int w = tid >> 6, l = tid & 63;

  if (blockIdx.z == 0) {  // ---- Q: streaming, no LDS, no barrier
    float4 reg[16];
    float ps[16];
#pragma unroll
    for (int it = 0; it < 16; ++it) {
      const int row = it * 4 + w;
      reg[it] = *(const float4*)(Q + ((size_t)b * SS + s0 + row) * DD + l * 4);
      ps[it] = reg[it].x * reg[it].x + reg[it].y * reg[it].y +
               reg[it].z * reg[it].z + reg[it].w * reg[it].w;
    }
#pragma unroll
    for (int off = 32; off; off >>= 1)
#pragma unroll
      for (int it = 0; it < 16; ++it) ps[it] += __shfl_xor(ps[it], off);
#pragma unroll
    for (int it = 0; it < 16; ++it) {
      const int row = it * 4 + w;
      const int m = mask[b * SS + s0 + row];
      const float ca = m ? 0.0f : (1.0f / ps[it]);
      const float aa = m ? NEGV : 0.0f;
      ushort4 o;
      o.x = f2bf(reg[it].x * ca + aa);
      o.y = f2bf(reg[it].y * ca + aa);
      o.z = f2bf(reg[it].z * ca + aa);
      o.w = f2bf(reg[it].w * ca + aa);
      *(ushort4*)(QS + ((size_t)b * SS + s0 + row) * DD + l * 4) = o;
    }
    return;
  }

  const int isK = (blockIdx.z == 1);
  const float* __restrict__ src = isK ? K : V;
  unsigned short* __restrict__ dst = isK ? KT : VT;

  float4 reg[16];
  float ps[16];
#pragma unroll
  for (int it = 0; it < 16; ++it) {
    const int row = it * 4 + w;
    reg[it] = *(const float4*)(src + ((size_t)b * SS + s0 + row) * DD + l * 4);
    ps[it] = reg[it].x * reg[it].x + reg[it].y * reg[it].y +
             reg[it].z * reg[it].z + reg[it].w * reg[it].w;
  }
  float scl[16];
  if (isK) {
#pragma unroll
    for (int off = 32; off; off >>= 1)
#pragma unroll
      for (int it = 0; it < 16; ++it) ps[it] += __shfl_xor(ps[it], off);
#pragma unroll
    for (int it = 0; it < 16; ++it) scl[it] = 1.0f / ps[it];
  } else {
#pragma unroll
    for (int it = 0; it < 16; ++it) scl[it] = 1.0f;
  }
#pragma unroll
  for (int it = 0; it < 16; ++it) {
    const int row = it * 4 + w;
    ushort4 o;
    o.x = f2bf(reg[it].x * scl[it]);
    o.y = f2bf(reg[it].y * scl[it]);
    o.z = f2bf(reg[it].z * scl[it]);
    o.w = f2bf(reg[it].w * scl[it]);
    *(ushort4*)(tile + row * 260 + l * 4) = o;
  }
  __syncthreads();
  // flush: thread tid owns d-row tid; 64 bf16 = 128B = two full 64B lines
  const size_t gbase = ((size_t)b * DD + tid) * SS + s0;
#pragma unroll
  for (int c = 0; c < 8; ++c) {
    union { unsigned short h[8]; uint4 v; } u;
#pragma unroll
    for (int j = 0; j < 8; ++j) u.h[j] = tile[(c * 8 + j) * 260 + tid];
    *(uint4*)(dst + gbase + c * 8) = u.v;
  }
}

// ---------------------------------------------------------------------------
// p2: part[y][b][e][d] = sum_{s in chunk y} VT[e][s]*KT[d][s].
// m97-style: global_load_lds(16B) staging, BK=64, no-pad LDS [row][64hw].
// ---------------------------------------------------------------------------
__global__ __launch_bounds__(256) void p2_kernel(
    const unsigned short* __restrict__ KT, const unsigned short* __restrict__ VT,
    float* __restrict__ part, int iters) {
  __shared__ unsigned short vt_l[128 * 64];
  __shared__ unsigned short kt_l[128 * 64];
  const int b = blockIdx.z;
  const int d0 = (blockIdx.x & 1) * 128;
  const int e0 = (blockIdx.x >> 1) * 128;
  const int sbeg = blockIdx.y * iters * 64;
  const int tid = threadIdx.x;
  const int w = tid >> 6, l = tid & 63;
  const int wr = w & 1, wc = w >> 1;
  const int quad = l >> 4, mr = l & 15;
  const int lr = l >> 3;         // row within 8-row chunk
  const int lc = (l & 7) * 8;    // hw col within 64

  f32x4 acc[4][4];
#pragma unroll
  for (int i = 0; i < 4; ++i)
#pragma unroll
    for (int j = 0; j < 4; ++j) acc[i][j] = (f32x4){0.f, 0.f, 0.f, 0.f};

  const size_t vbase = ((size_t)b * DD + e0) * SS;
  const size_t kbase = ((size_t)b * DD + d0) * SS;

  for (int ks = 0; ks < iters; ++ks) {
    const int sc = sbeg + ks * 64;
#pragma unroll
    for (int c = 0; c < 4; ++c) {
      const int r0 = w * 32 + c * 8;
      gload_lds16(VT + vbase + (size_t)(r0 + lr) * SS + sc + lc, vt_l + r0 * 64);
      gload_lds16(KT + kbase + (size_t)(r0 + lr) * SS + sc + lc, kt_l + r0 * 64);
    }
    __syncthreads();
#pragma unroll
    for (int kh = 0; kh < 2; ++kh) {
      s16x8 af[4], bfr[4];
#pragma unroll
      for (int i = 0; i < 4; ++i)
        af[i] = *(const s16x8*)(vt_l + (wr * 64 + i * 16 + mr) * 64 + kh * 32 + quad * 8);
#pragma unroll
      for (int j = 0; j < 4; ++j)
        bfr[j] = *(const s16x8*)(kt_l + (wc * 64 + j * 16 + mr) * 64 + kh * 32 + quad * 8);
#pragma unroll
      for (int i = 0; i < 4; ++i)
#pragma unroll
        for (int j = 0; j < 4; ++j)
          acc[i][j] = __builtin_amdgcn_mfma_f32_16x16x32_bf16(af[i], bfr[j],
                                                              acc[i][j], 0, 0, 0);
    }
    __syncthreads();
  }

  float* pb = part + ((size_t)blockIdx.y * BB + b) * DD * DD;
#pragma unroll
  for (int i = 0; i < 4; ++i) {
    const int e = e0 + wr * 64 + i * 16 + quad * 4;
#pragma unroll
    for (int j = 0; j < 4; ++j) {
      const int d = d0 + wc * 64 + j * 16 + mr;
      float* p = pb + (size_t)e * DD + d;
#pragma unroll
      for (int r = 0; r < 4; ++r) p[(size_t)r * DD] = acc[i][j][r];
    }
  }
}

// ---------------------------------------------------------------------------
// reduce: s1b[b][e][d] (bf16) = sum_p part[p][b][e][d]. L2/L3-resident.
// ---------------------------------------------------------------------------
__global__ __launch_bounds__(256) void reduce_kernel(
    const float* __restrict__ part, unsigned short* __restrict__ s1b,
    int split) {
  const size_t i4 = ((size_t)blockIdx.x * 256 + threadIdx.x) * 4;
  float ax = 0.f, ay = 0.f, az = 0.f, aw = 0.f;
  for (int p = 0; p < split; ++p) {
    const float4 v = *(const float4*)(part + (size_t)p * (BB * DD * DD) + i4);
    ax += v.x; ay += v.y; az += v.z; aw += v.w;
  }
  ushort4 o;
  o.x = f2bf(ax); o.y = f2bf(ay); o.z = f2bf(az); o.w = f2bf(aw);
  *(ushort4*)(s1b + i4) = o;
}

// ---------------------------------------------------------------------------
// p3: out[b][s][e] = (1/D) * sum_d QS[s][d] * s1b[e][d]. Same m97 K-loop.
// ---------------------------------------------------------------------------
__global__ __launch_bounds__(256) void p3_kernel(
    const unsigned short* __restrict__ QS, const unsigned short* __restrict__ s1b,
    float* __restrict__ out) {
  __shared__ unsigned short qs_l[128 * 64];
  __shared__ unsigned short s1_l[128 * 64];
  const int b = blockIdx.z;
  const int e0 = blockIdx.x * 128;
  const int s0 = blockIdx.y * 128;
  const int tid = threadIdx.x;
  const int w = tid >> 6, l = tid & 63;
  const int wr = w & 1, wc = w >> 1;
  const int quad = l >> 4, mr = l & 15;
  const int lr = l >> 3;
  const int lc = (l & 7) * 8;

  f32x4 acc[4][4];
#pragma unroll
  for (int i = 0; i < 4; ++i)
#pragma unroll
    for (int j = 0; j < 4; ++j) acc[i][j] = (f32x4){0.f, 0.f, 0.f, 0.f};

  for (int ks = 0; ks < 4; ++ks) {
    const int dc = ks * 64;
#pragma unroll
    for (int c = 0; c < 4; ++c) {
      const int r0 = w * 32 + c * 8;
      gload_lds16(QS + ((size_t)b * SS + s0 + r0 + lr) * DD + dc + lc,
                  qs_l + r0 * 64);
      gload_lds16(s1b + ((size_t)b * DD + e0 + r0 + lr) * DD + dc + lc,
                  s1_l + r0 * 64);
    }
    __syncthreads();
#pragma unroll
    for (int kh = 0; kh < 2; ++kh) {
      s16x8 af[4], bfr[4];
#pragma unroll
      for (int i = 0; i < 4; ++i)
        af[i] = *(const s16x8*)(qs_l + (wr * 64 + i * 16 + mr) * 64 + kh * 32 + quad * 8);
#pragma unroll
      for (int j = 0; j < 4; ++j)
        bfr[j] = *(const s16x8*)(s1_l + (wc * 64 + j * 16 + mr) * 64 + kh * 32 + quad * 8);
#pragma unroll
      for (int i = 0; i < 4; ++i)
#pragma unroll
        for (int j = 0; j < 4; ++j)
          acc[i][j] = __builtin_amdgcn_mfma_f32_16x16x32_bf16(af[i], bfr[j],
                                                              acc[i][j], 0, 0, 0);
    }
    __syncthreads();
  }

#pragma unroll
  for (int i = 0; i < 4; ++i) {
    const int s = s0 + wr * 64 + i * 16 + quad * 4;
#pragma unroll
    for (int j = 0; j < 4; ++j) {
      const int e = e0 + wc * 64 + j * 16 + mr;
      float* p = out + ((size_t)b * SS + s) * DD + e;
#pragma unroll
      for (int r = 0; r < 4; ++r) p[(size_t)r * DD] = acc[i][j][r] * (1.0f / DD);
    }
  }
}

extern "C" void kernel_launch(void* const* d_in, const int* in_sizes, int n_in,
                              void* d_out, int out_size, void* d_ws,
                              size_t ws_size, hipStream_t stream) {
  const float* Q = (const float*)d_in[0];
  const float* K = (const float*)d_in[1];
  const float* V = (const float*)d_in[2];
  const int* mask = (const int*)d_in[3];
  float* out = (float*)d_out;

  char* ws = (char*)d_ws;
  const size_t MB = (size_t)1024 * 1024;
  unsigned short* QS = (unsigned short*)(ws);            // bf16 [B][S][D] 16MB
  unsigned short* KT = (unsigned short*)(ws + 16 * MB);  // bf16 [B][D][S] 16MB
  unsigned short* VT = (unsigned short*)(ws + 32 * MB);  // bf16 [B][D][S] 16MB
  float* part = (float*)(ws + 48 * MB);                  // f32 [split][B][D][D]

  const int split = (ws_size >= (size_t)82 * MB) ? 16 : 8;
  const int iters = SS / (64 * split);  // K-chunks of 64 per p2 block
  unsigned short* s1b =
      (unsigned short*)(ws + 48 * MB + (size_t)split * 2 * MB);  // bf16 1MB

  prep_kernel<<<dim3(SS / 64, BB, 3), 256, 0, stream>>>(Q, K, V, mask, QS, KT,
                                                        VT);
  p2_kernel<<<dim3(4, split, BB), 256, 0, stream>>>(KT, VT, part, iters);
  reduce_kernel<<<dim3(512), 256, 0, stream>>>(part, s1b, split);
  p3_kernel<<<dim3(2, SS / 128, BB), 256, 0, stream>>>(QS, s1b, out);
}

// Round 4
// 178.032 us; speedup vs baseline: 1.0854x; 1.0115x over previous
//
#include <hip/hip_runtime.h>

#define BB 8
#define SS 4096
#define DD 256
#define NEGV -1000000000.0f

typedef float f32x4 __attribute__((ext_vector_type(4)));
typedef short s16x8 __attribute__((ext_vector_type(8)));

// float -> bf16 round-to-nearest-even (inputs finite)
static __device__ __forceinline__ unsigned short f2bf(float x) {
  unsigned int u = __builtin_bit_cast(unsigned int, x);
  u += 0x7fffu + ((u >> 16) & 1u);
  return (unsigned short)(u >> 16);
}

// async global->LDS, 16B per lane; LDS dest = wave-uniform base + lane*16
static __device__ __forceinline__ void gload_lds16(
    const unsigned short* __restrict__ g, unsigned short* l) {
  __builtin_amdgcn_global_load_lds(
      (const __attribute__((address_space(1))) void*)g,
      (__attribute__((address_space(3))) void*)l, 16, 0, 0);
}

// ---------------------------------------------------------------------------
// prep: grid (S/64, B, 3).
//  z=0: QS[b][s][d] = bf16(mask ? NEG : q/|q|^2)   (natural, no LDS)
//  z=1: KT[b][d][s] = bf16(k/|k|^2)                (LDS transpose)
//  z=2: VT[b][e][s] = bf16(v)                      (LDS transpose)
// __launch_bounds__(256,2): 256-VGPR budget so all 16 float4 row-loads stay
// in flight (R3 had VGPR=68 -> compiler chunked loads -> latency-serialized).
// ---------------------------------------------------------------------------
__global__ __launch_bounds__(256, 2) void prep_kernel(
    const float* __restrict__ Q, const float* __restrict__ K,
    const float* __restrict__ V, const int* __restrict__ mask,
    unsigned short* __restrict__ QS, unsigned short* __restrict__ KT,
    unsigned short* __restrict__ VT) {
  __shared__ unsigned short tile[64 * 260];
  const int b = blockIdx.y;
  const int s0 = blockIdx.x * 64;
  const int tid = threadIdx.x;
  const int w = tid >> 6, l = tid & 63;

  if (blockIdx.z == 0) {  // ---- Q: streaming, no LDS, no barrier
    float4 reg[16];
    float ps[16];
#pragma unroll
    for (int it = 0; it < 16; ++it) {
      const int row = it * 4 + w;
      reg[it] = *(const float4*)(Q + ((size_t)b * SS + s0 + row) * DD + l * 4);
    }
    int mk[16];
#pragma unroll
    for (int it = 0; it < 16; ++it) mk[it] = mask[b * SS + s0 + it * 4 + w];
#pragma unroll
    for (int it = 0; it < 16; ++it)
      ps[it] = reg[it].x * reg[it].x + reg[it].y * reg[it].y +
               reg[it].z * reg[it].z + reg[it].w * reg[it].w;
#pragma unroll
    for (int off = 32; off; off >>= 1)
#pragma unroll
      for (int it = 0; it < 16; ++it) ps[it] += __shfl_xor(ps[it], off);
#pragma unroll
    for (int it = 0; it < 16; ++it) {
      const int row = it * 4 + w;
      const float ca = mk[it] ? 0.0f : (1.0f / ps[it]);
      const float aa = mk[it] ? NEGV : 0.0f;
      ushort4 o;
      o.x = f2bf(reg[it].x * ca + aa);
      o.y = f2bf(reg[it].y * ca + aa);
      o.z = f2bf(reg[it].z * ca + aa);
      o.w = f2bf(reg[it].w * ca + aa);
      *(ushort4*)(QS + ((size_t)b * SS + s0 + row) * DD + l * 4) = o;
    }
    return;
  }

  const int isK = (blockIdx.z == 1);
  const float* __restrict__ src = isK ? K : V;
  unsigned short* __restrict__ dst = isK ? KT : VT;

  float4 reg[16];
  float ps[16];
#pragma unroll
  for (int it = 0; it < 16; ++it) {
    const int row = it * 4 + w;
    reg[it] = *(const float4*)(src + ((size_t)b * SS + s0 + row) * DD + l * 4);
  }
#pragma unroll
  for (int it = 0; it < 16; ++it)
    ps[it] = reg[it].x * reg[it].x + reg[it].y * reg[it].y +
             reg[it].z * reg[it].z + reg[it].w * reg[it].w;
  float scl[16];
  if (isK) {
#pragma unroll
    for (int off = 32; off; off >>= 1)
#pragma unroll
      for (int it = 0; it < 16; ++it) ps[it] += __shfl_xor(ps[it], off);
#pragma unroll
    for (int it = 0; it < 16; ++it) scl[it] = 1.0f / ps[it];
  } else {
#pragma unroll
    for (int it = 0; it < 16; ++it) scl[it] = 1.0f;
  }
#pragma unroll
  for (int it = 0; it < 16; ++it) {
    const int row = it * 4 + w;
    ushort4 o;
    o.x = f2bf(reg[it].x * scl[it]);
    o.y = f2bf(reg[it].y * scl[it]);
    o.z = f2bf(reg[it].z * scl[it]);
    o.w = f2bf(reg[it].w * scl[it]);
    *(ushort4*)(tile + row * 260 + l * 4) = o;
  }
  __syncthreads();
  // flush: thread tid owns d-row tid; 64 bf16 = 128B contiguous per thread
  const size_t gbase = ((size_t)b * DD + tid) * SS + s0;
#pragma unroll
  for (int c = 0; c < 8; ++c) {
    union { unsigned short h[8]; uint4 v; } u;
#pragma unroll
    for (int j = 0; j < 8; ++j) u.h[j] = tile[(c * 8 + j) * 260 + tid];
    *(uint4*)(dst + gbase + c * 8) = u.v;
  }
}

// ---------------------------------------------------------------------------
// p2: part[y][b][e][d] = sum_{s in chunk y} VT[e][s]*KT[d][s].
// BK=64 split into two kh-buffers of stride 32 hw: frag ds_read_b128 is
// bank-uniform (8 dw/bank, conflict-free); R3's single-stride-64 layout
// touched only 16 banks (2x LDS slowdown).
// ---------------------------------------------------------------------------
__global__ __launch_bounds__(256) void p2_kernel(
    const unsigned short* __restrict__ KT, const unsigned short* __restrict__ VT,
    float* __restrict__ part, int iters) {
  __shared__ unsigned short vt_l[2][128 * 32];
  __shared__ unsigned short kt_l[2][128 * 32];
  const int b = blockIdx.z;
  const int d0 = (blockIdx.x & 1) * 128;
  const int e0 = (blockIdx.x >> 1) * 128;
  const int sbeg = blockIdx.y * iters * 64;
  const int tid = threadIdx.x;
  const int w = tid >> 6, l = tid & 63;
  const int wr = w & 1, wc = w >> 1;
  const int quad = l >> 4, mr = l & 15;
  const int lr = l >> 2;        // row within 16-row group
  const int lc = (l & 3) * 8;   // hw col within 32

  f32x4 acc[4][4];
#pragma unroll
  for (int i = 0; i < 4; ++i)
#pragma unroll
    for (int j = 0; j < 4; ++j) acc[i][j] = (f32x4){0.f, 0.f, 0.f, 0.f};

  const size_t vbase = ((size_t)b * DD + e0) * SS;
  const size_t kbase = ((size_t)b * DD + d0) * SS;

  for (int ks = 0; ks < iters; ++ks) {
    const int sc = sbeg + ks * 64;
#pragma unroll
    for (int h = 0; h < 2; ++h)
#pragma unroll
      for (int g = 0; g < 2; ++g) {
        const int r0 = w * 32 + g * 16;
        gload_lds16(VT + vbase + (size_t)(r0 + lr) * SS + sc + h * 32 + lc,
                    &vt_l[h][r0 * 32]);
        gload_lds16(KT + kbase + (size_t)(r0 + lr) * SS + sc + h * 32 + lc,
                    &kt_l[h][r0 * 32]);
      }
    __syncthreads();
#pragma unroll
    for (int kh = 0; kh < 2; ++kh) {
      s16x8 af[4], bfr[4];
#pragma unroll
      for (int i = 0; i < 4; ++i)
        af[i] = *(const s16x8*)(&vt_l[kh][(wr * 64 + i * 16 + mr) * 32 + quad * 8]);
#pragma unroll
      for (int j = 0; j < 4; ++j)
        bfr[j] = *(const s16x8*)(&kt_l[kh][(wc * 64 + j * 16 + mr) * 32 + quad * 8]);
#pragma unroll
      for (int i = 0; i < 4; ++i)
#pragma unroll
        for (int j = 0; j < 4; ++j)
          acc[i][j] = __builtin_amdgcn_mfma_f32_16x16x32_bf16(af[i], bfr[j],
                                                              acc[i][j], 0, 0, 0);
    }
    __syncthreads();
  }

  float* pb = part + ((size_t)blockIdx.y * BB + b) * DD * DD;
#pragma unroll
  for (int i = 0; i < 4; ++i) {
    const int e = e0 + wr * 64 + i * 16 + quad * 4;
#pragma unroll
    for (int j = 0; j < 4; ++j) {
      const int d = d0 + wc * 64 + j * 16 + mr;
      float* p = pb + (size_t)e * DD + d;
#pragma unroll
      for (int r = 0; r < 4; ++r) p[(size_t)r * DD] = acc[i][j][r];
    }
  }
}

// ---------------------------------------------------------------------------
// reduce: s1b[b][e][d] (bf16) = sum_p part[p][b][e][d]. L2/L3-resident.
// ---------------------------------------------------------------------------
__global__ __launch_bounds__(256) void reduce_kernel(
    const float* __restrict__ part, unsigned short* __restrict__ s1b,
    int split) {
  const size_t i4 = ((size_t)blockIdx.x * 256 + threadIdx.x) * 4;
  float ax = 0.f, ay = 0.f, az = 0.f, aw = 0.f;
  for (int p = 0; p < split; ++p) {
    const float4 v = *(const float4*)(part + (size_t)p * (BB * DD * DD) + i4);
    ax += v.x; ay += v.y; az += v.z; aw += v.w;
  }
  ushort4 o;
  o.x = f2bf(ax); o.y = f2bf(ay); o.z = f2bf(az); o.w = f2bf(aw);
  *(ushort4*)(s1b + i4) = o;
}

// ---------------------------------------------------------------------------
// p3: out[b][s][e] = (1/D) * sum_d QS[s][d] * s1b[e][d]. Same kh-split LDS.
// ---------------------------------------------------------------------------
__global__ __launch_bounds__(256) void p3_kernel(
    const unsigned short* __restrict__ QS, const unsigned short* __restrict__ s1b,
    float* __restrict__ out) {
  __shared__ unsigned short qs_l[2][128 * 32];
  __shared__ unsigned short s1_l[2][128 * 32];
  const int b = blockIdx.z;
  const int e0 = blockIdx.x * 128;
  const int s0 = blockIdx.y * 128;
  const int tid = threadIdx.x;
  const int w = tid >> 6, l = tid & 63;
  const int wr = w & 1, wc = w >> 1;
  const int quad = l >> 4, mr = l & 15;
  const int lr = l >> 2;
  const int lc = (l & 3) * 8;

  f32x4 acc[4][4];
#pragma unroll
  for (int i = 0; i < 4; ++i)
#pragma unroll
    for (int j = 0; j < 4; ++j) acc[i][j] = (f32x4){0.f, 0.f, 0.f, 0.f};

  for (int ks = 0; ks < 4; ++ks) {
    const int dc = ks * 64;
#pragma unroll
    for (int h = 0; h < 2; ++h)
#pragma unroll
      for (int g = 0; g < 2; ++g) {
        const int r0 = w * 32 + g * 16;
        gload_lds16(QS + ((size_t)b * SS + s0 + r0 + lr) * DD + dc + h * 32 + lc,
                    &qs_l[h][r0 * 32]);
        gload_lds16(s1b + ((size_t)b * DD + e0 + r0 + lr) * DD + dc + h * 32 + lc,
                    &s1_l[h][r0 * 32]);
      }
    __syncthreads();
#pragma unroll
    for (int kh = 0; kh < 2; ++kh) {
      s16x8 af[4], bfr[4];
#pragma unroll
      for (int i = 0; i < 4; ++i)
        af[i] = *(const s16x8*)(&qs_l[kh][(wr * 64 + i * 16 + mr) * 32 + quad * 8]);
#pragma unroll
      for (int j = 0; j < 4; ++j)
        bfr[j] = *(const s16x8*)(&s1_l[kh][(wc * 64 + j * 16 + mr) * 32 + quad * 8]);
#pragma unroll
      for (int i = 0; i < 4; ++i)
#pragma unroll
        for (int j = 0; j < 4; ++j)
          acc[i][j] = __builtin_amdgcn_mfma_f32_16x16x32_bf16(af[i], bfr[j],
                                                              acc[i][j], 0, 0, 0);
    }
    __syncthreads();
  }

#pragma unroll
  for (int i = 0; i < 4; ++i) {
    const int s = s0 + wr * 64 + i * 16 + quad * 4;
#pragma unroll
    for (int j = 0; j < 4; ++j) {
      const int e = e0 + wc * 64 + j * 16 + mr;
      float* p = out + ((size_t)b * SS + s) * DD + e;
#pragma unroll
      for (int r = 0; r < 4; ++r) p[(size_t)r * DD] = acc[i][j][r] * (1.0f / DD);
    }
  }
}

extern "C" void kernel_launch(void* const* d_in, const int* in_sizes, int n_in,
                              void* d_out, int out_size, void* d_ws,
                              size_t ws_size, hipStream_t stream) {
  const float* Q = (const float*)d_in[0];
  const float* K = (const float*)d_in[1];
  const float* V = (const float*)d_in[2];
  const int* mask = (const int*)d_in[3];
  float* out = (float*)d_out;

  char* ws = (char*)d_ws;
  const size_t MB = (size_t)1024 * 1024;
  unsigned short* QS = (unsigned short*)(ws);            // bf16 [B][S][D] 16MB
  unsigned short* KT = (unsigned short*)(ws + 16 * MB);  // bf16 [B][D][S] 16MB
  unsigned short* VT = (unsigned short*)(ws + 32 * MB);  // bf16 [B][D][S] 16MB
  float* part = (float*)(ws + 48 * MB);                  // f32 [split][B][D][D]

  const int split = (ws_size >= (size_t)82 * MB) ? 16 : 8;
  const int iters = SS / (64 * split);  // K-chunks of 64 per p2 block
  unsigned short* s1b =
      (unsigned short*)(ws + 48 * MB + (size_t)split * 2 * MB);  // bf16 1MB

  prep_kernel<<<dim3(SS / 64, BB, 3), 256, 0, stream>>>(Q, K, V, mask, QS, KT,
                                                        VT);
  p2_kernel<<<dim3(4, split, BB), 256, 0, stream>>>(KT, VT, part, iters);
  reduce_kernel<<<dim3(512), 256, 0, stream>>>(part, s1b, split);
  p3_kernel<<<dim3(2, SS / 128, BB), 256, 0, stream>>>(QS, s1b, out);
}